// Round 2
// baseline (172.077 us; speedup 1.0000x reference)
//
#include <hip/hip_runtime.h>
#include <math.h>

#define NB 65536
#define IMGD 32
#define NPIX 1024
#define PSTRIDE 20

// Constant tables (same for every image) and per-image derived params.
// Kept as module __device__ globals so we never depend on ws_size.
__device__ float g_r[NPIX];
__device__ float g_th[NPIX];      // theta * 5/(2*pi)  (pre-folded for layer 11)
__device__ float g_par[(size_t)NB * PSTRIDE];

__global__ void init_tables_kernel() {
    int p = threadIdx.x;              // 1024 threads
    int x = p >> 5, y = p & 31;
    float dx = (float)(x - 16), dy = (float)(y - 16);
    // exact integer squares; sqrtf correctly rounded -> bitwise match with numpy
    g_r[p] = sqrtf(dx * dx + dy * dy);
    // theta = atan2(yy-CY, xx-CX); fold in 5/(2*pi) for revolution-based sin
    g_th[p] = atan2f(dy, dx) * 0.79577471545947668f;
}

__global__ void init_params_kernel(const float* __restrict__ W) {
    int b = blockIdx.x * blockDim.x + threadIdx.x;
    if (b >= NB) return;
    const float* w = W + (size_t)b * 16;
    float* P = g_par + (size_t)b * PSTRIDE;

    float w0 = w[0], w1 = w[1], w2 = w[2], w3 = w[3], w4 = w[4], w5 = w[5],
          w6 = w[6], w7 = w[7], w8 = w[8], w9 = w[9], w10 = w[10], w11 = w[11],
          w12 = w[12], w13 = w[13], w14 = w[14], w15 = w[15];

    P[0] = w0 * 5.0f;                                   // layer 0 amplitude
    // layer 1: half = floor(clip(|w1|*8, 2, 12)); |w1|*8 exact (pow2 mul)
    float half = floorf(fminf(fmaxf(fabsf(w1) * 8.0f, 2.0f), 12.0f));
    P[1] = 16.0f - half;                                // xlo (exact)
    P[2] = 16.0f + half;                                // xhi (exact)
    P[3] = w2 * 0.15625f;                               // layer2: rev per x  (10/64)
    P[4] = w3 * 0.15625f;                               // layer3: rev per y
    P[5] = w4 * 0.0390625f;                             // layer4: rev per (x+y) (5/128)
    P[6] = w5 * 0.15625f;                               // layer5: rev offset (10/64)
    P[7] = w6;                                          // bias
    // layer 7 blob center: trunc(16 + w7*5), mul/add un-fused to match ref
    float t7 = __fadd_rn(16.0f, __fmul_rn(w7, 5.0f));
    P[8] = truncf(t7);                                  // bx == by
    float sg = 4.0f + fabsf(w7) * 4.0f;
    P[9] = -1.0f / (2.0f * sg * sg);                    // natural-exp coefficient
    P[10] = w8 * 10.0f;                                 // ring radius (single mul, bit-match)
    // layer 9: cb = floor(clip(|w9|*8 + 2, 2, 16)); |w9|*8 exact, +2 un-fused
    float cb = floorf(fminf(fmaxf(__fadd_rn(fabsf(w9) * 8.0f, 2.0f), 2.0f), 16.0f));
    P[11] = cb;
    P[12] = 1.0f / cb;
    // layer 10: angle = w10 * f32(pi), rounded once (matches ref);
    // then cos/sin of that exact f32 value computed in DOUBLE and rounded to
    // f32 -> correctly-rounded result, matching numpy's <=0.56-ulp trig except
    // in a ~1e-16-relative window. (cosf/sinf f32 OCML was 1-2 ulp off ->
    // flipped the |rot|<3 mask on ~tens of border pixels = the 0.10 absmax.)
    float ang = __fmul_rn(w10, 3.14159265358979323846f);
    P[13] = (float)cos((double)ang);
    P[14] = (float)sin((double)ang);
    P[15] = w11;                                        // angular sinusoid scale
    P[16] = w12 * 0.1f;                                 // noise_randn coeff
    P[17] = w13 * 0.05f;                                // noise_rand coeff
    P[18] = 1.0f + w14;                                 // contrast
    P[19] = w15;                                        // inversion flag
}

// sin(2*pi*rev) via hardware v_sin_f32 (input in revolutions, fract-reduced)
__device__ __forceinline__ float hsin(float rev) {
    rev = rev - floorf(rev);
    return __builtin_amdgcn_sinf(rev);
}

// Exact floor(x/cb) for integer-valued x in [0,32), cb in [2,16]:
// reciprocal estimate then integer correction (all products exact in f32).
__device__ __forceinline__ float fdivq(float xf, float cb, float rcb) {
    float q = floorf(xf * rcb);
    q += ((q + 1.0f) * cb <= xf) ? 1.0f : 0.0f;
    q -= ((q * cb) > xf) ? 1.0f : 0.0f;
    return q;
}

__global__ __launch_bounds__(256) void decode_kernel(
        const float* __restrict__ nrand,   // noise_randn
        const float* __restrict__ nunif,   // noise_rand
        float* __restrict__ out) {
    int b = blockIdx.x;
    int t = threadIdx.x;
    const float* P = g_par + (size_t)b * PSTRIDE;

    float a0  = P[0],  xlo = P[1],  xhi = P[2],  s2  = P[3],  s3 = P[4];
    float s4  = P[5],  s5o = P[6],  w6  = P[7],  bxy = P[8],  nk = P[9];
    float t8  = P[10], cb  = P[11], rcb = P[12], ca  = P[13], sa = P[14];
    float w11 = P[15], k12 = P[16], k13 = P[17], con = P[18], w15 = P[19];

    int p0 = t * 4;                 // 4 consecutive pixels, same row x
    int x  = p0 >> 5;
    int y0 = p0 & 31;
    float xf = (float)x;

    // hoisted x-dependent work (shared by the 4 pixels)
    float sin2  = 0.5f * hsin(s2 * xf);
    bool  mrow  = (xf >= xlo) && (xf < xhi);
    float dxb   = xf - bxy;
    float dxb2  = dxb * dxb;
    float qx    = fdivq(xf, cb, rcb);
    float rotx  = __fmul_rn(ca, xf - 16.0f);

    size_t base = (size_t)b * NPIX + (size_t)p0;
    float4 vr = *reinterpret_cast<const float4*>(nrand + base);
    float4 vu = *reinterpret_cast<const float4*>(nunif + base);
    float4 rr = *reinterpret_cast<const float4*>(g_r + p0);
    float4 tt = *reinterpret_cast<const float4*>(g_th + p0);

    const float* rrp = reinterpret_cast<const float*>(&rr);
    const float* ttp = reinterpret_cast<const float*>(&tt);
    const float* vrp = reinterpret_cast<const float*>(&vr);
    const float* vup = reinterpret_cast<const float*>(&vu);

    float img[4];
    float mn = 1e30f, mx = -1e30f;

#pragma unroll
    for (int j = 0; j < 4; ++j) {
        float yf = (float)(y0 + j);
        float r  = rrp[j];
        float th = ttp[j];

        // layer 0: clipped radial cone
        float v = fminf(fmaxf(a0 - r, 0.0f), 1.0f);
        // layer 1: centered square (exact integer-boundary compares)
        v += (mrow && (yf >= xlo) && (yf < xhi)) ? 0.5f : 0.0f;
        // layers 2-4: sinusoids (hardware sin, revolutions)
        v += sin2;
        v += 0.5f * hsin(s3 * yf);
        v += 0.5f * hsin(s4 * (xf + yf));
        // layer 5: warp
        v += 0.5f * hsin(0.015625f * yf + s5o);
        // layer 6: bias
        v += w6;
        // layer 7: gaussian blob
        float dyb = yf - bxy;
        v += __expf((dxb2 + dyb * dyb) * nk);
        // layer 8: ring (bit-exact comparison: un-fused sub/mul)
        float dr = __fsub_rn(r, t8);
        v += (__fmul_rn(dr, dr) < 10.0f) ? 1.0f : 0.0f;
        // layer 9: checkerboard (exact integer floor-div)
        float qy = fdivq(yf, cb, rcb);
        float s  = qx + qy;
        float par = s - 2.0f * floorf(s * 0.5f);
        v += par * 0.3f;
        // layer 10: rotated line (un-fused to match ref rounding)
        float rot = __fadd_rn(rotx, __fmul_rn(sa, yf - 16.0f));
        v += (fabsf(rot) < 3.0f) ? 0.6f : 0.0f;
        // layer 11: angular sinusoid
        v += 0.5f * hsin(th * w11);
        // layers 12-13: noise
        v += vrp[j] * k12;
        v += (vup[j] - 0.5f) * k13;
        // layer 14: contrast
        v = (v - 0.5f) * con + 0.5f;
        // layer 15: conditional inversion
        v = (w15 > 0.0f) ? (1.0f - v) : v;

        img[j] = v;
        mn = fminf(mn, v);
        mx = fmaxf(mx, v);
    }

    // wave (64-lane) butterfly reduce
#pragma unroll
    for (int off = 32; off > 0; off >>= 1) {
        mn = fminf(mn, __shfl_xor(mn, off));
        mx = fmaxf(mx, __shfl_xor(mx, off));
    }
    __shared__ float smn[4], smx[4];
    int wid = t >> 6;
    if ((t & 63) == 0) { smn[wid] = mn; smx[wid] = mx; }
    __syncthreads();
    mn = fminf(fminf(smn[0], smn[1]), fminf(smn[2], smn[3]));
    mx = fmaxf(fmaxf(smx[0], smx[1]), fmaxf(smx[2], smx[3]));

    float inv = 1.0f / (mx - mn + 1e-8f);
    float4 o;
    o.x = (img[0] - mn) * inv;
    o.y = (img[1] - mn) * inv;
    o.z = (img[2] - mn) * inv;
    o.w = (img[3] - mn) * inv;
    *reinterpret_cast<float4*>(out + base) = o;
}

extern "C" void kernel_launch(void* const* d_in, const int* in_sizes, int n_in,
                              void* d_out, int out_size, void* d_ws, size_t ws_size,
                              hipStream_t stream) {
    const float* W  = (const float*)d_in[0];
    const float* nr = (const float*)d_in[1];
    const float* nu = (const float*)d_in[2];
    float* out = (float*)d_out;

    init_tables_kernel<<<1, 1024, 0, stream>>>();
    init_params_kernel<<<NB / 256, 256, 0, stream>>>(W);
    decode_kernel<<<NB, 256, 0, stream>>>(nr, nu, out);
}

// Round 3
// 148.667 us; speedup vs baseline: 1.1575x; 1.1575x over previous
//
#include <hip/hip_runtime.h>
#include <math.h>

#define NB 65536
#define IMGD 32
#define NPIX 1024
#define PSTRIDE 20

// Constant tables (same for every image) and per-image derived params.
__device__ float g_r[NPIX];
__device__ float g_th[NPIX];      // theta * 5/(2*pi)  (pre-folded for layer 11)
__device__ float g_par[(size_t)NB * PSTRIDE];

__global__ void init_tables_kernel() {
    int p = threadIdx.x;              // 1024 threads
    int x = p >> 5, y = p & 31;
    float dx = (float)(x - 16), dy = (float)(y - 16);
    // exact integer squares; sqrtf correctly rounded -> bitwise match with numpy
    g_r[p] = sqrtf(dx * dx + dy * dy);
    // theta = atan2(yy-CY, xx-CX); fold in 5/(2*pi) for revolution-based sin
    g_th[p] = atan2f(dy, dx) * 0.79577471545947668f;
}

__global__ void init_params_kernel(const float* __restrict__ W) {
    int b = blockIdx.x * blockDim.x + threadIdx.x;
    if (b >= NB) return;
    const float* w = W + (size_t)b * 16;
    float* P = g_par + (size_t)b * PSTRIDE;

    float w0 = w[0], w1 = w[1], w2 = w[2], w3 = w[3], w4 = w[4], w5 = w[5],
          w6 = w[6], w7 = w[7], w8 = w[8], w9 = w[9], w10 = w[10], w11 = w[11],
          w12 = w[12], w13 = w[13], w14 = w[14], w15 = w[15];

    P[0] = w0 * 5.0f;                                   // layer 0 amplitude
    // layer 1: half = floor(clip(|w1|*8, 2, 12)); |w1|*8 exact (pow2 mul)
    float half = floorf(fminf(fmaxf(fabsf(w1) * 8.0f, 2.0f), 12.0f));
    P[1] = 16.0f - half;                                // lo (exact)
    P[2] = 16.0f + half;                                // hi (exact)
    P[3] = w2 * 0.15625f;                               // layer2: rev per x  (10/64)
    P[4] = w3 * 0.15625f;                               // layer3: rev per y
    P[5] = w4 * 0.0390625f;                             // layer4: rev per (x+y) (5/128)
    P[6] = w5 * 0.15625f;                               // layer5: rev offset (10/64)
    P[7] = w6;                                          // bias
    // layer 7 blob center: trunc(16 + w7*5), mul/add un-fused to match ref
    float t7 = __fadd_rn(16.0f, __fmul_rn(w7, 5.0f));
    P[8] = truncf(t7);                                  // bx == by
    float sg = 4.0f + fabsf(w7) * 4.0f;
    P[9] = -1.0f / (2.0f * sg * sg);                    // natural-exp coefficient
    P[10] = w8 * 10.0f;                                 // ring radius (single mul, bit-match)
    // layer 9: cb = floor(clip(|w9|*8 + 2, 2, 16)); |w9|*8 exact, +2 un-fused
    float cb = floorf(fminf(fmaxf(__fadd_rn(fabsf(w9) * 8.0f, 2.0f), 2.0f), 16.0f));
    P[11] = cb;
    P[12] = 1.0f / cb;
    // layer 10: angle = w10 * f32(pi), rounded once (matches ref); cos/sin of
    // that exact f32 value in DOUBLE, rounded to f32 -> correctly-rounded,
    // matches numpy's <=0.56-ulp trig (1-2 ulp OCML f32 trig flipped the
    // |rot|<3 mask -> was the 0.10 absmax in round 1).
    float ang = __fmul_rn(w10, 3.14159265358979323846f);
    P[13] = (float)cos((double)ang);
    P[14] = (float)sin((double)ang);
    P[15] = w11;                                        // angular sinusoid scale
    P[16] = w12 * 0.1f;                                 // noise_randn coeff
    P[17] = w13 * 0.05f;                                // noise_rand coeff
    P[18] = 1.0f + w14;                                 // contrast
    P[19] = w15;                                        // inversion flag
}

// sin(2*pi*rev) via hardware v_sin_f32 (input in revolutions, fract-reduced)
__device__ __forceinline__ float hsin(float rev) {
    rev = rev - floorf(rev);
    return __builtin_amdgcn_sinf(rev);
}

// Exact floor(x/cb) for integer-valued x in [0,32), cb in [2,16]:
// reciprocal estimate then integer correction (all products exact in f32).
__device__ __forceinline__ float fdivq(float xf, float cb, float rcb) {
    float q = floorf(xf * rcb);
    q += ((q + 1.0f) * cb <= xf) ? 1.0f : 0.0f;
    q -= ((q * cb) > xf) ? 1.0f : 0.0f;
    return q;
}

// One block = one image. Per-image separable layers go to tiny LDS tables:
// per-pixel work is ~30 VALU + ONE v_sin (theta layer, genuinely 2D).
__global__ __launch_bounds__(256) void decode_kernel(
        const float* __restrict__ nrand,   // noise_randn
        const float* __restrict__ nunif,   // noise_rand
        float* __restrict__ out) {
    int b = blockIdx.x;
    int t = threadIdx.x;
    const float* P = g_par + (size_t)b * PSTRIDE;

    float a0  = P[0],  lo  = P[1],  hi  = P[2],  s2  = P[3],  s3 = P[4];
    float s4  = P[5],  s5o = P[6],  w6  = P[7],  bxy = P[8],  nk = P[9];
    float t8  = P[10], cb  = P[11], rcb = P[12], ca  = P[13], sa = P[14];
    float w11 = P[15], k12 = P[16], k13 = P[17], con = P[18], w15 = P[19];

    __shared__ float4 xt4[32];   // {0.5*sin2 + 0.3*px, xmask(0/1), -0.6*px, gx}
    __shared__ float4 yt4[32];   // {0.5*sin3 + 0.5*warp + 0.3*py + w6, ymask(0/0.5), py, gy}
    __shared__ float  stab[63];  // 0.5*sin4(x+y)

    if (t < 32) {
        float xf = (float)t;
        float qx = fdivq(xf, cb, rcb);
        float px = qx - 2.0f * floorf(qx * 0.5f);       // parity 0/1, exact
        float d  = xf - bxy;
        float4 e;
        e.x = 0.5f * hsin(s2 * xf) + 0.3f * px;
        e.y = (xf >= lo && xf < hi) ? 1.0f : 0.0f;
        e.z = -0.6f * px;
        e.w = __expf(d * d * nk);
        xt4[t] = e;
    } else if (t < 64) {
        float yf = (float)(t - 32);
        float qy = fdivq(yf, cb, rcb);
        float py = qy - 2.0f * floorf(qy * 0.5f);
        float d  = yf - bxy;
        float4 e;
        e.x = 0.5f * hsin(s3 * yf) + 0.5f * hsin(0.015625f * yf + s5o)
              + 0.3f * py + w6;
        e.y = (yf >= lo && yf < hi) ? 0.5f : 0.0f;
        e.z = py;
        e.w = __expf(d * d * nk);
        yt4[t - 32] = e;
    } else if (t < 127) {
        int s = t - 64;
        stab[s] = 0.5f * hsin(s4 * (float)s);
    }
    __syncthreads();

    int p0 = t * 4;                 // 4 consecutive pixels, same row x
    int x  = p0 >> 5;
    int y0 = p0 & 31;
    float xf = (float)x;

    float4 X   = xt4[x];
    float rotx = __fmul_rn(ca, xf - 16.0f);

    size_t base = (size_t)b * NPIX + (size_t)p0;
    float4 vr = *reinterpret_cast<const float4*>(nrand + base);
    float4 vu = *reinterpret_cast<const float4*>(nunif + base);
    float4 rr = *reinterpret_cast<const float4*>(g_r + p0);
    float4 tt = *reinterpret_cast<const float4*>(g_th + p0);

    const float* rrp = reinterpret_cast<const float*>(&rr);
    const float* ttp = reinterpret_cast<const float*>(&tt);
    const float* vrp = reinterpret_cast<const float*>(&vr);
    const float* vup = reinterpret_cast<const float*>(&vu);

    float img[4];
    float mn = 1e30f, mx = -1e30f;

#pragma unroll
    for (int j = 0; j < 4; ++j) {
        int   y  = y0 + j;
        float yf = (float)y;
        float r  = rrp[j];
        float4 Y = yt4[y];

        // layer 0: clipped radial cone
        float v = fminf(fmaxf(a0 - r, 0.0f), 1.0f);
        // separable sums: sin2(x) + sin3(y) + warp(y) + bias + checker 0.3(px+py)
        v += X.x + Y.x;
        // layer 1: centered square (exact integer-boundary masks)
        v = fmaf(X.y, Y.y, v);
        // layer 4: diagonal sinusoid
        v += stab[x + y];
        // checker cross term: -0.6*px*py  (completes 0.3*(px XOR py), exact)
        v = fmaf(X.z, Y.z, v);
        // layer 7: gaussian blob, exp split (<=4e-7 abs err)
        v = fmaf(X.w, Y.w, v);
        // layer 8: ring (bit-exact comparison: un-fused sub/mul)
        float dr = __fsub_rn(r, t8);
        v += (__fmul_rn(dr, dr) < 10.0f) ? 1.0f : 0.0f;
        // layer 10: rotated line (un-fused to match ref rounding)
        float rot = __fadd_rn(rotx, __fmul_rn(sa, yf - 16.0f));
        v += (fabsf(rot) < 3.0f) ? 0.6f : 0.0f;
        // layer 11: angular sinusoid — the one per-pixel transcendental
        v += 0.5f * hsin(ttp[j] * w11);
        // layers 12-13: noise
        v = fmaf(vrp[j], k12, v);
        v = fmaf(vup[j] - 0.5f, k13, v);

        img[j] = v;
        mn = fminf(mn, v);
        mx = fmaxf(mx, v);
    }

    // wave (64-lane) butterfly reduce on RAW v; contrast+inversion folded below
#pragma unroll
    for (int off = 32; off > 0; off >>= 1) {
        mn = fminf(mn, __shfl_xor(mn, off));
        mx = fmaxf(mx, __shfl_xor(mx, off));
    }
    __shared__ float smn[4], smx[4];
    int wid = t >> 6;
    if ((t & 63) == 0) { smn[wid] = mn; smx[wid] = mx; }
    __syncthreads();
    mn = fminf(fminf(smn[0], smn[1]), fminf(smn[2], smn[3]));
    mx = fmaxf(fmaxf(smx[0], smx[1]), fmaxf(smx[2], smx[3]));

    // contrast (v-0.5)*con+0.5, optional inversion, then min-max normalize:
    // affine => fold into one (v - base)*scale. Sign of con and w15>0 flip
    // together; epsilon term scales identically up to 1 ulp (harmless).
    float ac    = fabsf(con);
    float denom = fmaf(ac, mx - mn, 1e-8f);
    float s     = ac / denom;
    bool  eff   = (w15 > 0.0f) != (con < 0.0f);
    float bse   = eff ? mx : mn;
    float sgn   = eff ? -s : s;

    float4 o;
    o.x = (img[0] - bse) * sgn;
    o.y = (img[1] - bse) * sgn;
    o.z = (img[2] - bse) * sgn;
    o.w = (img[3] - bse) * sgn;
    *reinterpret_cast<float4*>(out + base) = o;
}

extern "C" void kernel_launch(void* const* d_in, const int* in_sizes, int n_in,
                              void* d_out, int out_size, void* d_ws, size_t ws_size,
                              hipStream_t stream) {
    const float* W  = (const float*)d_in[0];
    const float* nr = (const float*)d_in[1];
    const float* nu = (const float*)d_in[2];
    float* out = (float*)d_out;

    init_tables_kernel<<<1, 1024, 0, stream>>>();
    init_params_kernel<<<NB / 256, 256, 0, stream>>>(W);
    decode_kernel<<<NB, 256, 0, stream>>>(nr, nu, out);
}

// Round 4
// 147.195 us; speedup vs baseline: 1.1690x; 1.0100x over previous
//
#include <hip/hip_runtime.h>
#include <math.h>

#define NB 65536
#define IMGD 32
#define NPIX 1024
#define PSTRIDE 20

// Constant tables (same for every image) and per-image derived params.
__device__ float g_r[NPIX];
__device__ float g_th[NPIX];      // theta * 5/(2*pi)  (pre-folded for layer 11)
__device__ float g_par[(size_t)NB * PSTRIDE];

__global__ void init_params_kernel(const float* __restrict__ W) {
    int b = blockIdx.x * blockDim.x + threadIdx.x;

    // block 0 additionally fills the constant pixel tables (4 px/thread)
    if (blockIdx.x == 0) {
        int t = threadIdx.x;
        for (int k = 0; k < 4; ++k) {
            int p = t * 4 + k;
            int x = p >> 5, y = p & 31;
            float dx = (float)(x - 16), dy = (float)(y - 16);
            // exact integer squares; sqrtf correctly rounded -> bitwise match
            g_r[p] = sqrtf(dx * dx + dy * dy);
            // theta = atan2(yy-CY, xx-CX); fold 5/(2*pi) for revolution sin
            g_th[p] = atan2f(dy, dx) * 0.79577471545947668f;
        }
    }
    if (b >= NB) return;
    const float* w = W + (size_t)b * 16;
    float* P = g_par + (size_t)b * PSTRIDE;

    float w0 = w[0], w1 = w[1], w2 = w[2], w3 = w[3], w4 = w[4], w5 = w[5],
          w6 = w[6], w7 = w[7], w8 = w[8], w9 = w[9], w10 = w[10], w11 = w[11],
          w12 = w[12], w13 = w[13], w14 = w[14], w15 = w[15];

    P[0] = w0 * 5.0f;                                   // layer 0 amplitude
    // layer 1: half = floor(clip(|w1|*8, 2, 12)); |w1|*8 exact (pow2 mul)
    float half = floorf(fminf(fmaxf(fabsf(w1) * 8.0f, 2.0f), 12.0f));
    P[1] = 16.0f - half;                                // lo (exact)
    P[2] = 16.0f + half;                                // hi (exact)
    P[3] = w2 * 0.15625f;                               // layer2: rev per x  (10/64)
    P[4] = w3 * 0.15625f;                               // layer3: rev per y
    P[5] = w4 * 0.0390625f;                             // layer4: rev per (x+y) (5/128)
    P[6] = w5 * 0.15625f;                               // layer5: rev offset (10/64)
    P[7] = w6;                                          // bias
    // layer 7 blob center: trunc(16 + w7*5), mul/add un-fused to match ref
    float t7 = __fadd_rn(16.0f, __fmul_rn(w7, 5.0f));
    P[8] = truncf(t7);                                  // bx == by
    float sg = 4.0f + fabsf(w7) * 4.0f;
    P[9] = -1.0f / (2.0f * sg * sg);                    // natural-exp coefficient
    P[10] = w8 * 10.0f;                                 // ring radius (single mul)
    // layer 9: cb = floor(clip(|w9|*8 + 2, 2, 16)); |w9|*8 exact, +2 un-fused
    float cb = floorf(fminf(fmaxf(__fadd_rn(fabsf(w9) * 8.0f, 2.0f), 2.0f), 16.0f));
    P[11] = cb;
    P[12] = 1.0f / cb;
    // layer 10: angle = w10 * f32(pi) rounded once; cos/sin of that exact f32
    // computed in DOUBLE then rounded -> correctly-rounded f32, matches numpy
    // (OCML 1-2ulp f32 trig flipped the |rot|<3 mask -> round-1's 0.10 absmax).
    float ang = __fmul_rn(w10, 3.14159265358979323846f);
    P[13] = (float)cos((double)ang);
    P[14] = (float)sin((double)ang);
    P[15] = w11;                                        // angular sinusoid scale
    P[16] = w12 * 0.1f;                                 // noise_randn coeff
    P[17] = w13 * 0.05f;                                // noise_rand coeff
    P[18] = 1.0f + w14;                                 // contrast
    P[19] = w15;                                        // inversion flag
}

// sin(2*pi*rev) via hardware v_sin_f32 (input in revolutions, fract-reduced)
__device__ __forceinline__ float hsin(float rev) {
    rev = rev - floorf(rev);
    return __builtin_amdgcn_sinf(rev);
}

// Exact floor(x/cb) for integer-valued x in [0,32), cb in [2,16]:
// reciprocal estimate then integer correction (all products exact in f32).
__device__ __forceinline__ float fdivq(float xf, float cb, float rcb) {
    float q = floorf(xf * rcb);
    q += ((q + 1.0f) * cb <= xf) ? 1.0f : 0.0f;
    q -= ((q * cb) > xf) ? 1.0f : 0.0f;
    return q;
}

// One block = one image. Thread t owns pixels p = t + 256j (y = t&31 FIXED per
// thread, x varies): all y-derived work hoisted once per thread; xt4 reads are
// wave-broadcast (free), stab reads 2-way (free), yt4 read once via padded
// index (conflict-free). Per-pixel: ~22 VALU + one v_sin (theta layer).
__global__ __launch_bounds__(256) void decode_kernel(
        const float* __restrict__ nrand,   // noise_randn
        const float* __restrict__ nunif,   // noise_rand
        float* __restrict__ out) {
    int b = blockIdx.x;
    int t = threadIdx.x;
    const float* P = g_par + (size_t)b * PSTRIDE;

    float a0  = P[0],  lo  = P[1],  hi  = P[2],  s2  = P[3],  s3 = P[4];
    float s4  = P[5],  s5o = P[6],  w6  = P[7],  bxy = P[8],  nk = P[9];
    float t8  = P[10], cb  = P[11], rcb = P[12], ca  = P[13], sa = P[14];
    float w11 = P[15], k12 = P[16], k13 = P[17], con = P[18], w15 = P[19];

    __shared__ float4 xt4[32];   // {0.5*sin2 + 0.3*px, xmask(0/1), -0.6*px, gx}
    __shared__ float4 yt4[36];   // padded idx y+(y>>3): {ysum, ymask(0/0.5), py, gy}
    __shared__ float  stab[63];  // 0.5*sin4(x+y)

    if (t < 32) {
        float xf = (float)t;
        float qx = fdivq(xf, cb, rcb);
        float px = qx - 2.0f * floorf(qx * 0.5f);       // parity 0/1, exact
        float d  = xf - bxy;
        float4 e;
        e.x = 0.5f * hsin(s2 * xf) + 0.3f * px;
        e.y = (xf >= lo && xf < hi) ? 1.0f : 0.0f;
        e.z = -0.6f * px;
        e.w = __expf(d * d * nk);
        xt4[t] = e;
    } else if (t < 64) {
        int   y  = t - 32;
        float yf = (float)y;
        float qy = fdivq(yf, cb, rcb);
        float py = qy - 2.0f * floorf(qy * 0.5f);
        float d  = yf - bxy;
        float4 e;
        e.x = 0.5f * hsin(s3 * yf) + 0.5f * hsin(0.015625f * yf + s5o)
              + 0.3f * py + w6;
        e.y = (yf >= lo && yf < hi) ? 0.5f : 0.0f;
        e.z = py;
        e.w = __expf(d * d * nk);
        yt4[y + (y >> 3)] = e;
    } else if (t < 127) {
        int s = t - 64;
        stab[s] = 0.5f * hsin(s4 * (float)s);
    }
    __syncthreads();

    // per-thread (y-fixed) hoisted state
    int   y   = t & 31;
    int   x0  = t >> 5;                   // x for j=0; x = x0 + 8j
    float4 Y  = yt4[y + (y >> 3)];        // conflict-free padded read
    float yf  = (float)y;
    float sy  = __fmul_rn(sa, yf - 16.0f);   // rotated-line y term (un-fused)

    size_t base = (size_t)b * NPIX + (size_t)t;
    const float* nrp = nrand + base;
    const float* nup = nunif + base;
    const float* rp  = g_r + t;
    const float* tp  = g_th + t;

    float img[4];
    float mn = 1e30f, mx = -1e30f;

#pragma unroll
    for (int j = 0; j < 4; ++j) {
        int   x  = x0 + 8 * j;
        float xf = (float)x;
        float r  = rp[256 * j];
        float4 X = xt4[x];

        // layer 0: clipped radial cone
        float v = fminf(fmaxf(a0 - r, 0.0f), 1.0f);
        // separable sums: sin2(x)+0.3px + sin3(y)+warp(y)+0.3py+bias
        v += X.x + Y.x;
        // layer 1: centered square (exact integer-boundary masks)
        v = fmaf(X.y, Y.y, v);
        // layer 4: diagonal sinusoid
        v += stab[x + y];
        // checker cross term: -0.6*px*py (completes 0.3*(px XOR py), exact)
        v = fmaf(X.z, Y.z, v);
        // layer 7: gaussian blob, exp split (<=4e-7 abs err)
        v = fmaf(X.w, Y.w, v);
        // layer 8: ring (bit-exact: un-fused sub/mul on exact-sqrt r)
        float dr = __fsub_rn(r, t8);
        v += (__fmul_rn(dr, dr) < 10.0f) ? 1.0f : 0.0f;
        // layer 10: rotated line (mul, hoisted mul, add — all _rn, matches ref)
        float rot = __fadd_rn(__fmul_rn(ca, xf - 16.0f), sy);
        v += (fabsf(rot) < 3.0f) ? 0.6f : 0.0f;
        // layer 11: angular sinusoid — the one per-pixel transcendental
        v += 0.5f * hsin(tp[256 * j] * w11);
        // layers 12-13: noise
        v = fmaf(nrp[256 * j], k12, v);
        v = fmaf(nup[256 * j] - 0.5f, k13, v);

        img[j] = v;
        mn = fminf(mn, v);
        mx = fmaxf(mx, v);
    }

    // wave (64-lane) butterfly reduce on RAW v; contrast+inversion folded below
#pragma unroll
    for (int off = 32; off > 0; off >>= 1) {
        mn = fminf(mn, __shfl_xor(mn, off));
        mx = fmaxf(mx, __shfl_xor(mx, off));
    }
    __shared__ float smn[4], smx[4];
    int wid = t >> 6;
    if ((t & 63) == 0) { smn[wid] = mn; smx[wid] = mx; }
    __syncthreads();
    mn = fminf(fminf(smn[0], smn[1]), fminf(smn[2], smn[3]));
    mx = fmaxf(fmaxf(smx[0], smx[1]), fmaxf(smx[2], smx[3]));

    // contrast (v-0.5)*con+0.5, optional inversion, then min-max normalize:
    // affine => fold into one (v - base)*scale. Sign of con and w15>0 flip
    // together; epsilon term scales identically up to 1 ulp (harmless).
    float ac    = fabsf(con);
    float denom = fmaf(ac, mx - mn, 1e-8f);
    float s     = ac / denom;
    bool  eff   = (w15 > 0.0f) != (con < 0.0f);
    float bse   = eff ? mx : mn;
    float sgn   = eff ? -s : s;

    float* op = out + base;
#pragma unroll
    for (int j = 0; j < 4; ++j)
        op[256 * j] = (img[j] - bse) * sgn;
}

extern "C" void kernel_launch(void* const* d_in, const int* in_sizes, int n_in,
                              void* d_out, int out_size, void* d_ws, size_t ws_size,
                              hipStream_t stream) {
    const float* W  = (const float*)d_in[0];
    const float* nr = (const float*)d_in[1];
    const float* nu = (const float*)d_in[2];
    float* out = (float*)d_out;

    init_params_kernel<<<NB / 256, 256, 0, stream>>>(W);
    decode_kernel<<<NB, 256, 0, stream>>>(nr, nu, out);
}